// Round 14
// baseline (237.866 us; speedup 1.0000x reference)
//
#include <hip/hip_runtime.h>
#include <stdint.h>

// L2 1-NN, B=4096 x[B,256] vs N=32768 P[N,256] fp32.
// Round 14: low-register high-TLP screen. Root cause across R4-R13: hipcc
// allocates fewer VGPRs than live demand and rematerializes from LDS/global
// inside the loop (R13: demand ~150, VGPR_Count 88). Fix: wave tile 64x32 ->
// demand ~90 (acc[4][2]=32 + bv[4][2]=32 + transient av). A static in LDS
// (64KB/block); B loaded global->REGISTER with depth-4 statically-indexed
// ring (t&3==q&3), lead 2 bodies; NO manual vmcnt in the loop (compiler
// per-use waits). Keys merged via LDS atomicMin table, flushed once (no
// store-drain). LDS 80KB/block -> 2 blocks/CU = 16 waves/CU TLP.
// argmin_j (psq[j] - 2 x.p_j); x_sq drops out. Candidate set
// {64-col groups with groupmin <= approx_min + MARGIN} provably contains the
// exact argmin (MARGIN = 2.0 >= worst-case 2*bf16 screening error).

#define NB 4096
#define NP 32768
#define ND 256
#define NG 512             // N / 64 column groups
#define MARGIN 2.0f

typedef __attribute__((ext_vector_type(8))) __bf16 bf16x8;
typedef __attribute__((ext_vector_type(4))) __bf16 bf16x4;
typedef __attribute__((ext_vector_type(4))) float f32x4;

// ---- workspace layout (bytes) ----
static constexpr size_t OFF_PSQ = 0;                               // 32768 f32
static constexpr size_t OFF_XB  = 131072;                          // 4096x256 bf16
static constexpr size_t OFF_PB  = OFF_XB + (size_t)NB * ND * 2;    // 32768x256 bf16
static constexpr size_t OFF_BM  = OFF_PB + (size_t)NP * ND * 2;    // 4096x512 u32
static constexpr size_t WS_NEED = OFF_BM + (size_t)NB * NG * 4;    // 27,394,048

#define VMCNT(n) asm volatile("s_waitcnt vmcnt(" #n ")" ::: "memory")
#define LGKM(n)  asm volatile("s_waitcnt lgkmcnt(" #n ")" ::: "memory")

__device__ __forceinline__ void gload_lds16(const void* g, void* l) {
    __builtin_amdgcn_global_load_lds(
        (const __attribute__((address_space(1))) uint32_t*)g,
        (__attribute__((address_space(3))) uint32_t*)l, 16, 0, 0);
}
__device__ __forceinline__ unsigned fkey(float f) {
    unsigned u = __float_as_uint(f);
    return (u & 0x80000000u) ? ~u : (u | 0x80000000u);
}
__device__ __forceinline__ float fkey_inv(unsigned u) {
    unsigned o = (u & 0x80000000u) ? (u & 0x7FFFFFFFu) : ~u;
    return __uint_as_float(o);
}
__device__ __forceinline__ unsigned long long umin64(unsigned long long a,
                                                     unsigned long long b) {
    return a < b ? a : b;
}
__device__ __forceinline__ unsigned umin32(unsigned a, unsigned b) {
    return a < b ? a : b;
}

// ------------------------------------------------- prep: bf16 convert + psq
__global__ void prep_kernel(const float* __restrict__ X, const float* __restrict__ P,
                            float* __restrict__ psq, __bf16* __restrict__ Xb,
                            __bf16* __restrict__ Pb) {
    int row  = blockIdx.x * 4 + (threadIdx.x >> 6);  // one wave per row
    int lane = threadIdx.x & 63;
    if (row < NP) {
        f32x4 v = ((const f32x4*)(P + (size_t)row * ND))[lane];
        bf16x4 b;
        b.x = (__bf16)v.x; b.y = (__bf16)v.y; b.z = (__bf16)v.z; b.w = (__bf16)v.w;
        ((bf16x4*)(Pb + (size_t)row * ND))[lane] = b;
        float s = v.x*v.x + v.y*v.y + v.z*v.z + v.w*v.w;
        #pragma unroll
        for (int off = 32; off > 0; off >>= 1) s += __shfl_down(s, off);
        if (lane == 0) psq[row] = s;
    } else {
        int r = row - NP;   // < NB
        f32x4 v = ((const f32x4*)(X + (size_t)r * ND))[lane];
        bf16x4 b;
        b.x = (__bf16)v.x; b.y = (__bf16)v.y; b.z = (__bf16)v.z; b.w = (__bf16)v.w;
        ((bf16x4*)(Xb + (size_t)r * ND))[lane] = b;
    }
}

// -------- low-register screen: A in LDS, B in register ring, 16 waves/CU ----
// Grid 512 = 32 mblk x 16 splits (bid&15 = split; bid%8 = split%8 -> all
// same-split blocks on one XCD, 1MB B-panel L2-local). 512 thr = 8 waves
// (wm 0..1 x wn 0..3); wave tile 64 rows x 32 cols, acc[4][2].
// Sweep: split = 2048 cols = 16 n-tiles(128 cols; wave owns wn*32) x 8
// k-slabs = 128 bodies. Body t (nt=t>>3, q=t&7):
//   load bv[(q+2)&3] for body t+2 (2 x global 16B/lane, compiler-waited)
//   4x { ds_read av frag; 2 MFMA on bv[q&3] }   (per-use lgkm by compiler)
//   q==7: epilogue -> LDS atomicMin key table (no global stores in loop)
// Flush table once at end. Only manual sync: prologue VMCNT(0)+syncthreads.
__global__ __launch_bounds__(512, 2)
void nn_reg_kernel(const __bf16* __restrict__ Xb, const __bf16* __restrict__ Pb,
                   const float* __restrict__ psq,
                   unsigned* __restrict__ blockmin) {
    __shared__ __align__(16) char A_lds[65536];    // 128 rows x 256 k bf16
    __shared__ unsigned tbl[128][32];              // 16KB key table

    const int tid  = threadIdx.x;
    const int lane = tid & 63;
    const int wave = tid >> 6;
    const int wm = wave >> 2, wn = wave & 3;
    const int bid   = blockIdx.x;
    const int mblk  = bid >> 4;
    const int split = bid & 15;
    const int bm    = mblk * 128;
    const int Nb    = split * 2048;
    const int fr = lane & 15, kg = lane >> 4;
    const int wbase16 = (tid & ~63) * 16;

    // init key table (poison-safe: re-init every launch)
    #pragma unroll
    for (int i = 0; i < 8; ++i)
        ((unsigned*)tbl)[i * 512 + tid] = 0xFFFFFFFFu;

    // ---- stage A cooperatively: chunk c=(q*8+fm)*64+l (R10-proven layout) --
    #pragma unroll
    for (int i = 0; i < 8; ++i) {
        const int c  = i * 512 + tid;              // chunk 0..4095
        const int q  = c >> 9;                     // k-slab 0..7
        const int fm = (c >> 6) & 7;               // 16-row frag 0..7
        const int l  = c & 63;
        gload_lds16(Xb + (size_t)(bm + fm * 16 + (l & 15)) * ND +
                        q * 32 + (l >> 4) * 8,
                    A_lds + (size_t)(i * 512) * 16 + wbase16);
    }

    // ---- prefetch bodies 0,1 into bv[0],bv[1] (nt=0, slabs 0,1) ----
    bf16x8 bv[4][2];
    const __bf16* pb0 = Pb + (size_t)(Nb + wn * 32 + fr) * ND + kg * 8;
    #pragma unroll
    for (int tt = 0; tt < 2; ++tt) {
        bv[tt][0] = *(const bf16x8*)(pb0 + tt * 32);
        bv[tt][1] = *(const bf16x8*)(pb0 + (size_t)16 * ND + tt * 32);
    }

    VMCNT(0);                       // A fully landed (bv also drained - once)
    __syncthreads();                // publish A + tbl init

    f32x4 acc[4][2];
    #pragma unroll
    for (int i = 0; i < 4; ++i) {
        acc[i][0] = (f32x4){0.f, 0.f, 0.f, 0.f};
        acc[i][1] = (f32x4){0.f, 0.f, 0.f, 0.f};
    }

    #pragma unroll 1
    for (int nt = 0; nt < 16; ++nt) {
        #pragma unroll
        for (int q = 0; q < 8; ++q) {
            const int t = nt * 8 + q;
            // ---- prefetch body t+2 into slot (q+2)&3 (== (t+2)&3) ----
            {
                const int t2 = (t + 2 < 128) ? (t + 2) : t;   // tail: redundant
                const int colb2 = Nb + (t2 >> 3) * 128 + wn * 32;
                const __bf16* src = Pb + (size_t)(colb2 + fr) * ND +
                                    (t2 & 7) * 32 + kg * 8;
                bv[(q + 2) & 3][0] = *(const bf16x8*)(src);
                bv[(q + 2) & 3][1] = *(const bf16x8*)(src + (size_t)16 * ND);
            }
            // ---- compute body t on bv[q&3] ----
            __builtin_amdgcn_s_setprio(1);
            #pragma unroll
            for (int mi = 0; mi < 4; ++mi) {
                bf16x8 av = *(const bf16x8*)(A_lds +
                    (size_t)((q * 8 + wm * 4 + mi) * 64 + lane) * 16);
                acc[mi][0] = __builtin_amdgcn_mfma_f32_16x16x32_bf16(
                    av, bv[q & 3][0], acc[mi][0], 0, 0, 0);
                acc[mi][1] = __builtin_amdgcn_mfma_f32_16x16x32_bf16(
                    av, bv[q & 3][1], acc[mi][1], 0, 0, 0);
            }
            __builtin_amdgcn_s_setprio(0);

            if (q == 7) {
                // ---- tile epilogue: row-min over wave's 32 cols -> LDS tbl
                const int colb = Nb + nt * 128 + wn * 32;
                const float cq0 = psq[colb + fr];
                const float cq1 = psq[colb + 16 + fr];
                const int gl = nt * 2 + (wn >> 1);
                #pragma unroll
                for (int mi = 0; mi < 4; ++mi) {
                    #pragma unroll
                    for (int r = 0; r < 4; ++r) {
                        float d = fminf(fmaf(-2.f, acc[mi][0][r], cq0),
                                        fmaf(-2.f, acc[mi][1][r], cq1));
                        #pragma unroll
                        for (int m = 1; m < 16; m <<= 1)
                            d = fminf(d, __shfl_xor(d, m));
                        if (fr == 0)
                            atomicMin(&tbl[wm * 64 + mi * 16 + kg * 4 + r][gl],
                                      fkey(d));
                    }
                }
                #pragma unroll
                for (int i = 0; i < 4; ++i) {
                    acc[i][0] = (f32x4){0.f, 0.f, 0.f, 0.f};
                    acc[i][1] = (f32x4){0.f, 0.f, 0.f, 0.f};
                }
            }
        }
    }

    // ---- flush key table: 4096 u32, coalesced ----
    __syncthreads();
    const int row = tid >> 2;
    const int gb  = (tid & 3) * 8;
    uint4 v0 = *(const uint4*)&tbl[row][gb];
    uint4 v1 = *(const uint4*)&tbl[row][gb + 4];
    unsigned* dst = &blockmin[(size_t)(bm + row) * NG + split * 32 + gb];
    *(uint4*)(dst)     = v0;
    *(uint4*)(dst + 4) = v1;
}

// ---------------- rescore: one wave per row, barrier-free -------------------
__global__ __launch_bounds__(512, 2)
void rescore_wave_kernel(const float* __restrict__ X, const float* __restrict__ P,
                         const float* __restrict__ psq,
                         const unsigned* __restrict__ blockmin,
                         float* __restrict__ out) {
    __shared__ float Xs[8][256];
    __shared__ unsigned short wcand[8][512];
    __shared__ int wcnt[8];

    const int tid = threadIdx.x, lane = tid & 63, wv = tid >> 6;
    const int row = blockIdx.x * 8 + wv;

    ((f32x4*)Xs[wv])[lane] = ((const f32x4*)(X + (size_t)row * ND))[lane];
    if (lane == 0) wcnt[wv] = 0;

    const unsigned* bmr = blockmin + (size_t)row * NG;
    uint4 ka = ((const uint4*)bmr)[lane * 2];
    uint4 kb = ((const uint4*)bmr)[lane * 2 + 1];
    unsigned km = umin32(umin32(umin32(ka.x, ka.y), umin32(ka.z, ka.w)),
                         umin32(umin32(kb.x, kb.y), umin32(kb.z, kb.w)));
    #pragma unroll
    for (int m = 1; m < 64; m <<= 1) km = umin32(km, __shfl_xor(km, m));
    const unsigned thr = fkey(fkey_inv(km) + MARGIN);

    const unsigned k8[8] = {ka.x, ka.y, ka.z, ka.w, kb.x, kb.y, kb.z, kb.w};
    #pragma unroll
    for (int i = 0; i < 8; ++i)
        if (k8[i] <= thr)
            wcand[wv][atomicAdd(&wcnt[wv], 1)] = (unsigned short)(lane * 8 + i);
    LGKM(0);                             // same-wave DS ops complete, in order
    const int n = wcnt[wv];

    unsigned long long best = 0xFFFFFFFFFFFFFFFFull;
    const f32x4* x4 = (const f32x4*)Xs[wv];
    for (int c = 0; c < n; ++c) {
        const int col = (int)wcand[wv][c] * 64 + lane;
        const f32x4* p4 = (const f32x4*)(P + (size_t)col * ND);
        float s = 0.f;
        #pragma unroll 16
        for (int i = 0; i < 64; ++i) {
            f32x4 pv = p4[i], xv = x4[i];
            s = fmaf(xv.x, pv.x, s); s = fmaf(xv.y, pv.y, s);
            s = fmaf(xv.z, pv.z, s); s = fmaf(xv.w, pv.w, s);
        }
        float d = fmaf(-2.f, s, psq[col]);
        best = umin64(best, ((unsigned long long)fkey(d) << 32) |
                            (unsigned long long)(unsigned)col);
    }
    #pragma unroll
    for (int m = 1; m < 64; m <<= 1)
        best = umin64(best, __shfl_xor(best, m));
    const unsigned bc = (unsigned)(best & 0xFFFFFFFFull);
    ((f32x4*)(out + (size_t)row * ND))[lane] =
        ((const f32x4*)(P + (size_t)bc * ND))[lane];
}

// ======================= fallback: exact fp32 path (small ws) ===============
#define BM1 128
#define BN1 128
#define BK1 32
#define LDA1 132

__global__ void psq_init_kernel(const float* __restrict__ P, float* __restrict__ psq,
                                unsigned long long* __restrict__ minpack) {
    int row  = blockIdx.x * 4 + (threadIdx.x >> 6);
    int lane = threadIdx.x & 63;
    float4 p4 = ((const float4*)(P + (size_t)row * ND))[lane];
    float s = p4.x*p4.x + p4.y*p4.y + p4.z*p4.z + p4.w*p4.w;
    #pragma unroll
    for (int off = 32; off > 0; off >>= 1) s += __shfl_down(s, off);
    if (lane == 0) psq[row] = s;
    int gid = blockIdx.x * blockDim.x + threadIdx.x;
    if (gid < NB) minpack[gid] = 0xFFFFFFFFFFFFFFFFull;
}

__global__ __launch_bounds__(256, 2)
void nn_main_kernel(const float* __restrict__ X, const float* __restrict__ P,
                    const float* __restrict__ psq,
                    unsigned long long* __restrict__ minpack) {
    __shared__ __align__(16) char smem_raw[2 * BK1 * LDA1 * 4];
    float (*As)[LDA1] = (float (*)[LDA1])smem_raw;
    float (*Bs)[LDA1] = (float (*)[LDA1])(smem_raw + BK1 * LDA1 * 4);
    const int bm  = blockIdx.y * BM1;
    const int bn  = blockIdx.x * BN1;
    const int tid = threadIdx.x;
    const int tx  = tid & 15;
    const int ty  = tid >> 4;
    float acc[8][8];
    #pragma unroll
    for (int i = 0; i < 8; ++i)
        #pragma unroll
        for (int j = 0; j < 8; ++j) acc[i][j] = 0.f;
    const int lrow = tid >> 3;
    const int lk   = (tid & 7) * 4;
    for (int k0 = 0; k0 < ND; k0 += BK1) {
        #pragma unroll
        for (int p = 0; p < 4; ++p) {
            int r = p * 32 + lrow;
            float4 aa = *(const float4*)(X + (size_t)(bm + r) * ND + k0 + lk);
            As[lk+0][r] = aa.x; As[lk+1][r] = aa.y; As[lk+2][r] = aa.z; As[lk+3][r] = aa.w;
            float4 bb = *(const float4*)(P + (size_t)(bn + r) * ND + k0 + lk);
            Bs[lk+0][r] = bb.x; Bs[lk+1][r] = bb.y; Bs[lk+2][r] = bb.z; Bs[lk+3][r] = bb.w;
        }
        __syncthreads();
        #pragma unroll 4
        for (int k = 0; k < BK1; ++k) {
            float4 a0 = *(const float4*)&As[k][ty*8];
            float4 a1 = *(const float4*)&As[k][ty*8 + 4];
            float4 b0 = *(const float4*)&Bs[k][tx*4];
            float4 b1 = *(const float4*)&Bs[k][64 + tx*4];
            float av2[8] = {a0.x,a0.y,a0.z,a0.w,a1.x,a1.y,a1.z,a1.w};
            float bv2[8] = {b0.x,b0.y,b0.z,b0.w,b1.x,b1.y,b1.z,b1.w};
            #pragma unroll
            for (int i = 0; i < 8; ++i)
                #pragma unroll
                for (int j = 0; j < 8; ++j)
                    acc[i][j] = fmaf(av2[i], bv2[j], acc[i][j]);
        }
        __syncthreads();
    }
    unsigned long long (*red)[16] = (unsigned long long (*)[16])smem_raw;
    float cj[8];
    int   jglob[8];
    #pragma unroll
    for (int j = 0; j < 8; ++j) {
        int c = (j < 4) ? (tx*4 + j) : (64 + tx*4 + (j - 4));
        jglob[j] = bn + c;
        cj[j]    = psq[bn + c];
    }
    #pragma unroll
    for (int i = 0; i < 8; ++i) {
        float bestv = 0.f; unsigned bidx = 0u; bool first = true;
        #pragma unroll
        for (int j = 0; j < 8; ++j) {
            float s = fmaf(-2.f, acc[i][j], cj[j]);
            if (first || s < bestv) { bestv = s; bidx = (unsigned)jglob[j]; first = false; }
        }
        unsigned u = fkey(bestv);
        red[ty*8 + i][tx] = ((unsigned long long)u << 32) | (unsigned long long)bidx;
    }
    __syncthreads();
    if (tid < BM1) {
        unsigned long long m = red[tid][0];
        #pragma unroll
        for (int t = 1; t < 16; ++t) m = umin64(m, red[tid][t]);
        atomicMin(&minpack[bm + tid], m);
    }
}

__global__ void gather_kernel(const float* __restrict__ P,
                              const unsigned long long* __restrict__ minpack,
                              float* __restrict__ out) {
    int row = blockIdx.x;
    unsigned idx = (unsigned)(minpack[row] & 0xFFFFFFFFull);
    int lane = threadIdx.x;
    ((float4*)(out + (size_t)row * ND))[lane] =
        ((const float4*)(P + (size_t)idx * ND))[lane];
}

// ------------------------------------------------------------------- launch
extern "C" void kernel_launch(void* const* d_in, const int* in_sizes, int n_in,
                              void* d_out, int out_size, void* d_ws, size_t ws_size,
                              hipStream_t stream) {
    const float* X = (const float*)d_in[0];
    const float* P = (const float*)d_in[1];
    float* out = (float*)d_out;
    char* w = (char*)d_ws;

    if (ws_size >= WS_NEED) {
        float* psq = (float*)(w + OFF_PSQ);
        __bf16* Xb = (__bf16*)(w + OFF_XB);
        __bf16* Pb = (__bf16*)(w + OFF_PB);
        unsigned* blockmin = (unsigned*)(w + OFF_BM);

        prep_kernel<<<(NP + NB) / 4, 256, 0, stream>>>(X, P, psq, Xb, Pb);
        nn_reg_kernel<<<(NB / 128) * 16, 512, 0, stream>>>(Xb, Pb, psq,
                                                           blockmin);
        rescore_wave_kernel<<<NB / 8, 512, 0, stream>>>(X, P, psq, blockmin, out);
    } else {
        float* psq = (float*)w;
        unsigned long long* minpack = (unsigned long long*)(w + (size_t)NP * 4);
        psq_init_kernel<<<NP / 4, 256, 0, stream>>>(P, psq, minpack);
        dim3 grid(NP / BN1, NB / BM1);
        nn_main_kernel<<<grid, dim3(256), 0, stream>>>(X, P, psq, minpack);
        gather_kernel<<<NB, 64, 0, stream>>>(P, minpack, out);
    }
}

// Round 15
// 231.772 us; speedup vs baseline: 1.0263x; 1.0263x over previous
//
#include <hip/hip_runtime.h>
#include <stdint.h>

// L2 1-NN, B=4096 x[B,256] vs N=32768 P[N,256] fp32.
// Round 15: A-in-REGISTERS with anti-remat. Pipe arithmetic: A+B both from
// LDS makes the LDS pipe binding (7.5 cyc/MFMA > 4.85 MFMA); A-in-regs drops
// LDS to ~3.9. R9 tried this and the compiler rematerialized the A-panel from
// global inside the loop (VGPR_Count=128 < demand, FETCH 25GB vs 16.5GB).
// Fix: after loading each A fragment, asm volatile("":"+v"(frag)) makes it
// opaque -> cannot be re-derived -> stays resident. Budget 128a+32bv+64acc+
// ~20 temps ~= 245 <= 256 @ launch_bounds(512,2). B ring = R10's proven
// race-free discipline: VMCNT(4) -> s_barrier -> bv reads -> stage(t+3).
// argmin_j (psq[j] - 2 x.p_j); x_sq drops out. Candidate set
// {64-col groups with groupmin <= approx_min + MARGIN} provably contains the
// exact argmin (MARGIN = 2.0 >= worst-case 2*bf16 screening error).

#define NB 4096
#define NP 32768
#define ND 256
#define NG 512             // N / 64 column groups
#define MARGIN 2.0f
#define NSPLIT 8
#define CPB 4096           // cols per split (NP / NSPLIT)

typedef __attribute__((ext_vector_type(8))) __bf16 bf16x8;
typedef __attribute__((ext_vector_type(4))) __bf16 bf16x4;
typedef __attribute__((ext_vector_type(4))) float f32x4;

// ---- workspace layout (bytes) ----
static constexpr size_t OFF_PSQ = 0;                               // 32768 f32
static constexpr size_t OFF_XB  = 131072;                          // 4096x256 bf16
static constexpr size_t OFF_PB  = OFF_XB + (size_t)NB * ND * 2;    // 32768x256 bf16
static constexpr size_t OFF_BM  = OFF_PB + (size_t)NP * ND * 2;    // 4096x512 u32
static constexpr size_t WS_NEED = OFF_BM + (size_t)NB * NG * 4;    // 27,394,048

#define VMCNT(n) asm volatile("s_waitcnt vmcnt(" #n ")" ::: "memory")
#define LGKM(n)  asm volatile("s_waitcnt lgkmcnt(" #n ")" ::: "memory")

__device__ __forceinline__ void gload_lds16(const void* g, void* l) {
    __builtin_amdgcn_global_load_lds(
        (const __attribute__((address_space(1))) uint32_t*)g,
        (__attribute__((address_space(3))) uint32_t*)l, 16, 0, 0);
}
// Anti-remat: make a loaded value opaque so the allocator must keep it
// resident instead of re-loading it from memory inside the loop.
__device__ __forceinline__ void opaque(bf16x8& v) {
    asm volatile("" : "+v"(v));
}
__device__ __forceinline__ unsigned fkey(float f) {
    unsigned u = __float_as_uint(f);
    return (u & 0x80000000u) ? ~u : (u | 0x80000000u);
}
__device__ __forceinline__ float fkey_inv(unsigned u) {
    unsigned o = (u & 0x80000000u) ? (u & 0x7FFFFFFFu) : ~u;
    return __uint_as_float(o);
}
__device__ __forceinline__ unsigned long long umin64(unsigned long long a,
                                                     unsigned long long b) {
    return a < b ? a : b;
}
__device__ __forceinline__ unsigned umin32(unsigned a, unsigned b) {
    return a < b ? a : b;
}

// ------------------------------------------------- prep: bf16 convert + psq
__global__ void prep_kernel(const float* __restrict__ X, const float* __restrict__ P,
                            float* __restrict__ psq, __bf16* __restrict__ Xb,
                            __bf16* __restrict__ Pb) {
    int row  = blockIdx.x * 4 + (threadIdx.x >> 6);  // one wave per row
    int lane = threadIdx.x & 63;
    if (row < NP) {
        f32x4 v = ((const f32x4*)(P + (size_t)row * ND))[lane];
        bf16x4 b;
        b.x = (__bf16)v.x; b.y = (__bf16)v.y; b.z = (__bf16)v.z; b.w = (__bf16)v.w;
        ((bf16x4*)(Pb + (size_t)row * ND))[lane] = b;
        float s = v.x*v.x + v.y*v.y + v.z*v.z + v.w*v.w;
        #pragma unroll
        for (int off = 32; off > 0; off >>= 1) s += __shfl_down(s, off);
        if (lane == 0) psq[row] = s;
    } else {
        int r = row - NP;   // < NB
        f32x4 v = ((const f32x4*)(X + (size_t)r * ND))[lane];
        bf16x4 b;
        b.x = (__bf16)v.x; b.y = (__bf16)v.y; b.z = (__bf16)v.z; b.w = (__bf16)v.w;
        ((bf16x4*)(Xb + (size_t)r * ND))[lane] = b;
    }
}

// ------------- A-in-registers N-sweep screen (anti-remat, ring B) -----------
// Grid 256 = 32 mblk x 8 split (bid&7 -> XCD-local 2MB B-panel); 1 block/CU.
// 512 thr = 8 waves (wm 0..1 x wn 0..3); wave tile 64 rows x 64 cols,
// acc[4][4]; A a[4][8] = wave's 64 rows x K=256 held in 128 VGPRs (opaque).
// Sweep: 128 bodies (body t: n-tile t>>3, 32-k slab t&7). B piece = 256 cols
// x 32 k = 16KB; ring 4x16KB, slot t&3, stage lead 3 (2 gload_lds/thread).
// Body t: VMCNT(4) [own stage(t) drained; t+1,t+2 in flight]; s_barrier
// [ALL waves' stage(t) published]; sched_barrier; bv[4] <- slot t&3 (single-
// buffered; compiler lgkm before MFMA); stage(t+3) [WAR: slot (t+3)&3 ==
// (t-1)&3, whose readers lgkm-retired before their MFMA in body t-1, which
// precedes barrier(t)]; 16 MFMA; q==7: epilogue (psq loads + key stores;
// later VMCNT(4) over-drains them oldest-first - conservative-safe).
__global__ __launch_bounds__(512, 2)
void nn_areg_kernel(const __bf16* __restrict__ Xb, const __bf16* __restrict__ Pb,
                    const float* __restrict__ psq,
                    unsigned* __restrict__ blockmin) {
    __shared__ __align__(16) char ring[65536];     // 4 x 16KB

    const int tid  = threadIdx.x;
    const int lane = tid & 63;
    const int wave = tid >> 6;
    const int wm = wave >> 2, wn = wave & 3;
    const int bid    = blockIdx.x;
    const int nsplit = bid & 7;
    const int mblk   = bid >> 3;
    const int bm     = mblk * 128;
    const int Nb     = nsplit * CPB;
    const int fr = lane & 15, kg = lane >> 4;
    const int wbase16 = (tid & ~63) * 16;

    // ---- A panel into registers, then make opaque (no remat possible) ----
    bf16x8 a[4][8];
    #pragma unroll
    for (int mi = 0; mi < 4; ++mi)
        #pragma unroll
        for (int q = 0; q < 8; ++q)
            a[mi][q] = *(const bf16x8*)(Xb +
                (size_t)(bm + wm * 64 + mi * 16 + fr) * ND + q * 32 + kg * 8);
    #pragma unroll
    for (int mi = 0; mi < 4; ++mi)
        #pragma unroll
        for (int q = 0; q < 8; ++q)
            opaque(a[mi][q]);      // forces waitcnt + pins values in VGPRs

    f32x4 acc[4][4];
    #pragma unroll
    for (int i = 0; i < 4; ++i)
        #pragma unroll
        for (int j = 0; j < 4; ++j) acc[i][j] = (f32x4){0.f, 0.f, 0.f, 0.f};

    auto stage = [&](int p) {
        char* dst = ring + (size_t)(p & 3) * 16384;
        const int colb = Nb + (p >> 3) * 256;
        const int kq   = p & 7;
        #pragma unroll
        for (int i = 0; i < 2; ++i) {
            const int c = i * 512 + tid;          // chunk 0..1023
            const int fn = c >> 6;
            const int l  = c & 63;
            gload_lds16(Pb + (size_t)(colb + fn * 16 + (l & 15)) * ND +
                            kq * 32 + (l >> 4) * 8,
                        dst + i * 8192 + wbase16);
        }
    };

    // ---- prologue: pieces 0..2 (A already drained by opaque's waitcnt) ----
    stage(0); stage(1); stage(2);

    #pragma unroll 1
    for (int nt = 0; nt < 16; ++nt) {
        #pragma unroll
        for (int q = 0; q < 8; ++q) {
            const int t = nt * 8 + q;
            if (t <= 125)      { VMCNT(4); }   // own stage(t) drained
            else if (t == 126) { VMCNT(2); }
            else               { VMCNT(0); }
            __builtin_amdgcn_s_barrier();      // ALL waves' stage(t) published
            __builtin_amdgcn_sched_barrier(0);
            const char* pc = ring + (size_t)(t & 3) * 16384;
            bf16x8 bv[4];
            #pragma unroll
            for (int ni = 0; ni < 4; ++ni)
                bv[ni] = *(const bf16x8*)(pc +
                    (size_t)((wn * 4 + ni) * 64 + lane) * 16);
            if (t <= 124) stage(t + 3);
            __builtin_amdgcn_s_setprio(1);
            #pragma unroll
            for (int mi = 0; mi < 4; ++mi)
                #pragma unroll
                for (int ni = 0; ni < 4; ++ni)
                    acc[mi][ni] = __builtin_amdgcn_mfma_f32_16x16x32_bf16(
                        a[mi][q], bv[ni], acc[mi][ni], 0, 0, 0);
            __builtin_amdgcn_s_setprio(0);

            if (q == 7) {
                // ---- tile epilogue: min over wave's 64 cols -> global keys
                const int colb = Nb + nt * 256 + wn * 64;
                float cq[4];
                #pragma unroll
                for (int ni = 0; ni < 4; ++ni)
                    cq[ni] = psq[colb + ni * 16 + fr];
                const int g = nsplit * 64 + nt * 4 + wn;
                #pragma unroll
                for (int mi = 0; mi < 4; ++mi) {
                    #pragma unroll
                    for (int r = 0; r < 4; ++r) {
                        float d = fmaf(-2.f, acc[mi][0][r], cq[0]);
                        #pragma unroll
                        for (int ni = 1; ni < 4; ++ni)
                            d = fminf(d, fmaf(-2.f, acc[mi][ni][r], cq[ni]));
                        #pragma unroll
                        for (int m = 1; m < 16; m <<= 1)
                            d = fminf(d, __shfl_xor(d, m));
                        if (fr == 0)
                            blockmin[(size_t)(bm + wm * 64 + mi * 16 + kg * 4
                                              + r) * NG + g] = fkey(d);
                    }
                }
                #pragma unroll
                for (int i = 0; i < 4; ++i)
                    #pragma unroll
                    for (int j = 0; j < 4; ++j)
                        acc[i][j] = (f32x4){0.f, 0.f, 0.f, 0.f};
            }
        }
    }
}

// ---------------- rescore: one wave per row, barrier-free -------------------
__global__ __launch_bounds__(512, 2)
void rescore_wave_kernel(const float* __restrict__ X, const float* __restrict__ P,
                         const float* __restrict__ psq,
                         const unsigned* __restrict__ blockmin,
                         float* __restrict__ out) {
    __shared__ float Xs[8][256];
    __shared__ unsigned short wcand[8][512];
    __shared__ int wcnt[8];

    const int tid = threadIdx.x, lane = tid & 63, wv = tid >> 6;
    const int row = blockIdx.x * 8 + wv;

    ((f32x4*)Xs[wv])[lane] = ((const f32x4*)(X + (size_t)row * ND))[lane];
    if (lane == 0) wcnt[wv] = 0;

    const unsigned* bmr = blockmin + (size_t)row * NG;
    uint4 ka = ((const uint4*)bmr)[lane * 2];
    uint4 kb = ((const uint4*)bmr)[lane * 2 + 1];
    unsigned km = umin32(umin32(umin32(ka.x, ka.y), umin32(ka.z, ka.w)),
                         umin32(umin32(kb.x, kb.y), umin32(kb.z, kb.w)));
    #pragma unroll
    for (int m = 1; m < 64; m <<= 1) km = umin32(km, __shfl_xor(km, m));
    const unsigned thr = fkey(fkey_inv(km) + MARGIN);

    const unsigned k8[8] = {ka.x, ka.y, ka.z, ka.w, kb.x, kb.y, kb.z, kb.w};
    #pragma unroll
    for (int i = 0; i < 8; ++i)
        if (k8[i] <= thr)
            wcand[wv][atomicAdd(&wcnt[wv], 1)] = (unsigned short)(lane * 8 + i);
    LGKM(0);                             // same-wave DS ops complete, in order
    const int n = wcnt[wv];

    unsigned long long best = 0xFFFFFFFFFFFFFFFFull;
    const f32x4* x4 = (const f32x4*)Xs[wv];
    for (int c = 0; c < n; ++c) {
        const int col = (int)wcand[wv][c] * 64 + lane;
        const f32x4* p4 = (const f32x4*)(P + (size_t)col * ND);
        float s = 0.f;
        #pragma unroll 16
        for (int i = 0; i < 64; ++i) {
            f32x4 pv = p4[i], xv = x4[i];
            s = fmaf(xv.x, pv.x, s); s = fmaf(xv.y, pv.y, s);
            s = fmaf(xv.z, pv.z, s); s = fmaf(xv.w, pv.w, s);
        }
        float d = fmaf(-2.f, s, psq[col]);
        best = umin64(best, ((unsigned long long)fkey(d) << 32) |
                            (unsigned long long)(unsigned)col);
    }
    #pragma unroll
    for (int m = 1; m < 64; m <<= 1)
        best = umin64(best, __shfl_xor(best, m));
    const unsigned bc = (unsigned)(best & 0xFFFFFFFFull);
    ((f32x4*)(out + (size_t)row * ND))[lane] =
        ((const f32x4*)(P + (size_t)bc * ND))[lane];
}

// ======================= fallback: exact fp32 path (small ws) ===============
#define BM1 128
#define BN1 128
#define BK1 32
#define LDA1 132

__global__ void psq_init_kernel(const float* __restrict__ P, float* __restrict__ psq,
                                unsigned long long* __restrict__ minpack) {
    int row  = blockIdx.x * 4 + (threadIdx.x >> 6);
    int lane = threadIdx.x & 63;
    float4 p4 = ((const float4*)(P + (size_t)row * ND))[lane];
    float s = p4.x*p4.x + p4.y*p4.y + p4.z*p4.z + p4.w*p4.w;
    #pragma unroll
    for (int off = 32; off > 0; off >>= 1) s += __shfl_down(s, off);
    if (lane == 0) psq[row] = s;
    int gid = blockIdx.x * blockDim.x + threadIdx.x;
    if (gid < NB) minpack[gid] = 0xFFFFFFFFFFFFFFFFull;
}

__global__ __launch_bounds__(256, 2)
void nn_main_kernel(const float* __restrict__ X, const float* __restrict__ P,
                    const float* __restrict__ psq,
                    unsigned long long* __restrict__ minpack) {
    __shared__ __align__(16) char smem_raw[2 * BK1 * LDA1 * 4];
    float (*As)[LDA1] = (float (*)[LDA1])smem_raw;
    float (*Bs)[LDA1] = (float (*)[LDA1])(smem_raw + BK1 * LDA1 * 4);
    const int bm  = blockIdx.y * BM1;
    const int bn  = blockIdx.x * BN1;
    const int tid = threadIdx.x;
    const int tx  = tid & 15;
    const int ty  = tid >> 4;
    float acc[8][8];
    #pragma unroll
    for (int i = 0; i < 8; ++i)
        #pragma unroll
        for (int j = 0; j < 8; ++j) acc[i][j] = 0.f;
    const int lrow = tid >> 3;
    const int lk   = (tid & 7) * 4;
    for (int k0 = 0; k0 < ND; k0 += BK1) {
        #pragma unroll
        for (int p = 0; p < 4; ++p) {
            int r = p * 32 + lrow;
            float4 aa = *(const float4*)(X + (size_t)(bm + r) * ND + k0 + lk);
            As[lk+0][r] = aa.x; As[lk+1][r] = aa.y; As[lk+2][r] = aa.z; As[lk+3][r] = aa.w;
            float4 bb = *(const float4*)(P + (size_t)(bn + r) * ND + k0 + lk);
            Bs[lk+0][r] = bb.x; Bs[lk+1][r] = bb.y; Bs[lk+2][r] = bb.z; Bs[lk+3][r] = bb.w;
        }
        __syncthreads();
        #pragma unroll 4
        for (int k = 0; k < BK1; ++k) {
            float4 a0 = *(const float4*)&As[k][ty*8];
            float4 a1 = *(const float4*)&As[k][ty*8 + 4];
            float4 b0 = *(const float4*)&Bs[k][tx*4];
            float4 b1 = *(const float4*)&Bs[k][64 + tx*4];
            float av2[8] = {a0.x,a0.y,a0.z,a0.w,a1.x,a1.y,a1.z,a1.w};
            float bv2[8] = {b0.x,b0.y,b0.z,b0.w,b1.x,b1.y,b1.z,b1.w};
            #pragma unroll
            for (int i = 0; i < 8; ++i)
                #pragma unroll
                for (int j = 0; j < 8; ++j)
                    acc[i][j] = fmaf(av2[i], bv2[j], acc[i][j]);
        }
        __syncthreads();
    }
    unsigned long long (*red)[16] = (unsigned long long (*)[16])smem_raw;
    float cj[8];
    int   jglob[8];
    #pragma unroll
    for (int j = 0; j < 8; ++j) {
        int c = (j < 4) ? (tx*4 + j) : (64 + tx*4 + (j - 4));
        jglob[j] = bn + c;
        cj[j]    = psq[bn + c];
    }
    #pragma unroll
    for (int i = 0; i < 8; ++i) {
        float bestv = 0.f; unsigned bidx = 0u; bool first = true;
        #pragma unroll
        for (int j = 0; j < 8; ++j) {
            float s = fmaf(-2.f, acc[i][j], cj[j]);
            if (first || s < bestv) { bestv = s; bidx = (unsigned)jglob[j]; first = false; }
        }
        unsigned u = fkey(bestv);
        red[ty*8 + i][tx] = ((unsigned long long)u << 32) | (unsigned long long)bidx;
    }
    __syncthreads();
    if (tid < BM1) {
        unsigned long long m = red[tid][0];
        #pragma unroll
        for (int t = 1; t < 16; ++t) m = umin64(m, red[tid][t]);
        atomicMin(&minpack[bm + tid], m);
    }
}

__global__ void gather_kernel(const float* __restrict__ P,
                              const unsigned long long* __restrict__ minpack,
                              float* __restrict__ out) {
    int row = blockIdx.x;
    unsigned idx = (unsigned)(minpack[row] & 0xFFFFFFFFull);
    int lane = threadIdx.x;
    ((float4*)(out + (size_t)row * ND))[lane] =
        ((const float4*)(P + (size_t)idx * ND))[lane];
}

// ------------------------------------------------------------------- launch
extern "C" void kernel_launch(void* const* d_in, const int* in_sizes, int n_in,
                              void* d_out, int out_size, void* d_ws, size_t ws_size,
                              hipStream_t stream) {
    const float* X = (const float*)d_in[0];
    const float* P = (const float*)d_in[1];
    float* out = (float*)d_out;
    char* w = (char*)d_ws;

    if (ws_size >= WS_NEED) {
        float* psq = (float*)(w + OFF_PSQ);
        __bf16* Xb = (__bf16*)(w + OFF_XB);
        __bf16* Pb = (__bf16*)(w + OFF_PB);
        unsigned* blockmin = (unsigned*)(w + OFF_BM);

        prep_kernel<<<(NP + NB) / 4, 256, 0, stream>>>(X, P, psq, Xb, Pb);
        nn_areg_kernel<<<(NB / 128) * NSPLIT, 512, 0, stream>>>(Xb, Pb, psq,
                                                                blockmin);
        rescore_wave_kernel<<<NB / 8, 512, 0, stream>>>(X, P, psq, blockmin, out);
    } else {
        float* psq = (float*)w;
        unsigned long long* minpack = (unsigned long long*)(w + (size_t)NP * 4);
        psq_init_kernel<<<NP / 4, 256, 0, stream>>>(P, psq, minpack);
        dim3 grid(NP / BN1, NB / BM1);
        nn_main_kernel<<<grid, dim3(256), 0, stream>>>(X, P, psq, minpack);
        gather_kernel<<<NB, 64, 0, stream>>>(P, minpack, out);
    }
}

// Round 16
// 169.860 us; speedup vs baseline: 1.4004x; 1.3645x over previous
//
#include <hip/hip_runtime.h>
#include <stdint.h>

// L2 1-NN, B=4096 x[B,256] vs N=32768 P[N,256] fp32.
// Round 16: R10 (A-in-LDS, proven clean: VGPR 100, 0 spill, 0 conflicts)
// with a VMEM-free, LDS-pipe-free epilogue:
//  - DPP 16-lane min-reduce (VALU) replaces shfl-xor (512 ds_bpermute/CU per
//    8 bodies on the contended LDS pipe),
//  - keys -> 32KB LDS table (one plain write per entry), flushed once,
//  - psq cq[4] prefetched at q==0 (3 bodies ahead); vmcnt wait table adjusted
//    (q in {1,2}: VMCNT(6), else VMCNT(2); exact tail) so counted waits stay
//    pure -- loop has ZERO VMEM besides staging.
// A-in-registers is dead: R9/R11/R15 all show the allocator caps at 128 arch
// VGPRs and remats/spills (R15: WRITE_SIZE 20GB of scratch).
// argmin_j (psq[j] - 2 x.p_j); x_sq drops out. Candidate set
// {64-col groups with groupmin <= approx_min + MARGIN} provably contains the
// exact argmin (MARGIN = 2.0 >= worst-case 2*bf16 screening error).

#define NB 4096
#define NP 32768
#define ND 256
#define NG 512             // N / 64 column groups
#define MARGIN 2.0f
#define NSPLIT 8
#define CPB 4096           // cols per split (NP / NSPLIT)

typedef __attribute__((ext_vector_type(8))) __bf16 bf16x8;
typedef __attribute__((ext_vector_type(4))) __bf16 bf16x4;
typedef __attribute__((ext_vector_type(4))) float f32x4;

// ---- workspace layout (bytes) ----
static constexpr size_t OFF_PSQ = 0;                               // 32768 f32
static constexpr size_t OFF_XB  = 131072;                          // 4096x256 bf16
static constexpr size_t OFF_PB  = OFF_XB + (size_t)NB * ND * 2;    // 32768x256 bf16
static constexpr size_t OFF_BM  = OFF_PB + (size_t)NP * ND * 2;    // 4096x512 u32
static constexpr size_t WS_NEED = OFF_BM + (size_t)NB * NG * 4;    // 27,394,048

#define VMCNT(n) asm volatile("s_waitcnt vmcnt(" #n ")" ::: "memory")
#define LGKM(n)  asm volatile("s_waitcnt lgkmcnt(" #n ")" ::: "memory")

__device__ __forceinline__ void gload_lds16(const void* g, void* l) {
    __builtin_amdgcn_global_load_lds(
        (const __attribute__((address_space(1))) uint32_t*)g,
        (__attribute__((address_space(3))) uint32_t*)l, 16, 0, 0);
}
// 16-lane min-reduce entirely on the VALU pipe (DPP), matching the MFMA C
// fragment layout (reduce lanes = one DPP row of 16).
__device__ __forceinline__ float dppmin16(float v) {
    int x;
    x = __builtin_amdgcn_update_dpp(0, __float_as_int(v), 0xB1, 0xF, 0xF, true);
    v = fminf(v, __int_as_float(x));   // quad_perm(1,0,3,2)  xor1
    x = __builtin_amdgcn_update_dpp(0, __float_as_int(v), 0x4E, 0xF, 0xF, true);
    v = fminf(v, __int_as_float(x));   // quad_perm(2,3,0,1)  xor2
    x = __builtin_amdgcn_update_dpp(0, __float_as_int(v), 0x141, 0xF, 0xF, true);
    v = fminf(v, __int_as_float(x));   // row_half_mirror     -> min over 8
    x = __builtin_amdgcn_update_dpp(0, __float_as_int(v), 0x140, 0xF, 0xF, true);
    v = fminf(v, __int_as_float(x));   // row_mirror          -> min over 16
    return v;
}
__device__ __forceinline__ unsigned fkey(float f) {
    unsigned u = __float_as_uint(f);
    return (u & 0x80000000u) ? ~u : (u | 0x80000000u);
}
__device__ __forceinline__ float fkey_inv(unsigned u) {
    unsigned o = (u & 0x80000000u) ? (u & 0x7FFFFFFFu) : ~u;
    return __uint_as_float(o);
}
__device__ __forceinline__ unsigned long long umin64(unsigned long long a,
                                                     unsigned long long b) {
    return a < b ? a : b;
}
__device__ __forceinline__ unsigned umin32(unsigned a, unsigned b) {
    return a < b ? a : b;
}

// ------------------------------------------------- prep: bf16 convert + psq
__global__ void prep_kernel(const float* __restrict__ X, const float* __restrict__ P,
                            float* __restrict__ psq, __bf16* __restrict__ Xb,
                            __bf16* __restrict__ Pb) {
    int row  = blockIdx.x * 4 + (threadIdx.x >> 6);  // one wave per row
    int lane = threadIdx.x & 63;
    if (row < NP) {
        f32x4 v = ((const f32x4*)(P + (size_t)row * ND))[lane];
        bf16x4 b;
        b.x = (__bf16)v.x; b.y = (__bf16)v.y; b.z = (__bf16)v.z; b.w = (__bf16)v.w;
        ((bf16x4*)(Pb + (size_t)row * ND))[lane] = b;
        float s = v.x*v.x + v.y*v.y + v.z*v.z + v.w*v.w;
        #pragma unroll
        for (int off = 32; off > 0; off >>= 1) s += __shfl_down(s, off);
        if (lane == 0) psq[row] = s;
    } else {
        int r = row - NP;   // < NB
        f32x4 v = ((const f32x4*)(X + (size_t)r * ND))[lane];
        bf16x4 b;
        b.x = (__bf16)v.x; b.y = (__bf16)v.y; b.z = (__bf16)v.z; b.w = (__bf16)v.w;
        ((bf16x4*)(Xb + (size_t)r * ND))[lane] = b;
    }
}

// ------------- A-in-LDS N-sweep screen, DPP epilogue, LDS key table ---------
// Grid 256 = 32 mblk x 8 split (bid&7 -> XCD-local 2MB B-panel); 1 block/CU.
// 512 thr = 8 waves (wm 0..1 x wn 0..3); wave tile 64 rows x 64 cols,
// acc[4][4]. Sweep: 128 bodies (body t: n-tile t>>3, 32-k slab t&7). B piece
// = 256 cols x 32 k = 16KB; ring 4x16KB, slot t&3, stage lead 3.
// Body t: VMCNT(see table) [own stage(t+1) drained]; s_barrier [ALL waves'
// stage(t+1) published]; sched_barrier; read av/bv for t+1 (read-ahead, R10-
// proven WAR chain); stage(t+3); q==0: prefetch cq[4]; 16 MFMA on [cur];
// q==7: DPP-reduce epilogue -> LDS tbl (no VMEM). Flush tbl once at end.
// vmcnt table (steady): q==0: Q=[s+1,s+2](4)->VMCNT(2); q==1,2: Q=8 (cq4 in
// queue) -> VMCNT(6); q==3: VMCNT(2) (drains cq+stage); q>=4: VMCNT(2).
// Tail: t==126,127 -> VMCNT(0). Verified body-by-body incl. first/last tile.
__global__ __launch_bounds__(512, 2)
void nn_dpp_kernel(const __bf16* __restrict__ Xb, const __bf16* __restrict__ Pb,
                   const float* __restrict__ psq,
                   unsigned* __restrict__ blockmin) {
    __shared__ __align__(16) char smem[163840];
    char* ring  = smem;                                   // 4 x 16KB
    char* A_lds = smem + 65536;                           // 64KB
    unsigned (*tbl)[64] = (unsigned (*)[64])(smem + 131072);  // 128x64 u32

    const int tid  = threadIdx.x;
    const int lane = tid & 63;
    const int wave = tid >> 6;
    const int wm = wave >> 2, wn = wave & 3;
    const int bid    = blockIdx.x;
    const int nsplit = bid & 7;
    const int mblk   = bid >> 3;
    const int bm     = mblk * 128;
    const int Nb     = nsplit * CPB;
    const int fr = lane & 15, kg = lane >> 4;
    const int wbase16 = (tid & ~63) * 16;

    f32x4 acc[4][4];
    #pragma unroll
    for (int i = 0; i < 4; ++i)
        #pragma unroll
        for (int j = 0; j < 4; ++j) acc[i][j] = (f32x4){0.f, 0.f, 0.f, 0.f};

    auto stage = [&](int p) {
        char* dst = ring + (size_t)(p & 3) * 16384;
        const int colb = Nb + (p >> 3) * 256;
        const int kq   = p & 7;
        #pragma unroll
        for (int i = 0; i < 2; ++i) {
            const int c = i * 512 + tid;          // chunk 0..1023
            const int fn = c >> 6;
            const int l  = c & 63;
            gload_lds16(Pb + (size_t)(colb + fn * 16 + (l & 15)) * ND +
                            kq * 32 + (l >> 4) * 8,
                        dst + i * 8192 + wbase16);
        }
    };

    // ---- prologue: A (8 issues) + pieces 0..2 ----
    #pragma unroll
    for (int i = 0; i < 8; ++i) {
        const int c  = i * 512 + tid;              // chunk 0..4095
        const int q  = c >> 9;                     // k-slab 0..7
        const int fm = (c >> 6) & 7;               // 16-row frag 0..7
        const int l  = c & 63;
        gload_lds16(Xb + (size_t)(bm + fm * 16 + (l & 15)) * ND +
                        q * 32 + (l >> 4) * 8,
                    A_lds + (size_t)(i * 512) * 16 + wbase16);
    }
    stage(0); stage(1); stage(2);
    VMCNT(4);                                  // A(8)+s0 drained; s1,s2 fly
    __builtin_amdgcn_s_barrier();              // A + slot0 published
    __builtin_amdgcn_sched_barrier(0);

    bf16x8 av[2][4], bv[2][4];
    #pragma unroll
    for (int mi = 0; mi < 4; ++mi)
        av[0][mi] = *(const bf16x8*)(A_lds +
            (size_t)((wm * 4 + mi) * 64 + lane) * 16);
    #pragma unroll
    for (int ni = 0; ni < 4; ++ni)
        bv[0][ni] = *(const bf16x8*)(ring +
            (size_t)((wn * 4 + ni) * 64 + lane) * 16);

    #pragma unroll 1
    for (int nt = 0; nt < 16; ++nt) {
        float cq[4];
        #pragma unroll
        for (int q = 0; q < 8; ++q) {
            const int t = nt * 8 + q;
            const int cur = q & 1, nxt = cur ^ 1;
            if (t >= 126)            { VMCNT(0); }
            else if (q == 1 || q == 2) { VMCNT(6); }
            else                     { VMCNT(2); }
            __builtin_amdgcn_s_barrier();      // ALL waves' stage(t+1) done
            __builtin_amdgcn_sched_barrier(0);
            if (t < 127) {
                const int qn = (q + 1) & 7;
                #pragma unroll
                for (int mi = 0; mi < 4; ++mi)
                    av[nxt][mi] = *(const bf16x8*)(A_lds +
                        (size_t)((qn * 8 + wm * 4 + mi) * 64 + lane) * 16);
                const char* pc = ring + (size_t)((t + 1) & 3) * 16384;
                #pragma unroll
                for (int ni = 0; ni < 4; ++ni)
                    bv[nxt][ni] = *(const bf16x8*)(pc +
                        (size_t)((wn * 4 + ni) * 64 + lane) * 16);
            }
            if (t <= 124) stage(t + 3);
            if (q == 0) {
                const int colb = Nb + nt * 256 + wn * 64;
                #pragma unroll
                for (int ni = 0; ni < 4; ++ni)
                    cq[ni] = psq[colb + ni * 16 + fr];   // drains by q==3
            }
            __builtin_amdgcn_s_setprio(1);
            #pragma unroll
            for (int mi = 0; mi < 4; ++mi)
                #pragma unroll
                for (int ni = 0; ni < 4; ++ni)
                    acc[mi][ni] = __builtin_amdgcn_mfma_f32_16x16x32_bf16(
                        av[cur][mi], bv[cur][ni], acc[mi][ni], 0, 0, 0);
            __builtin_amdgcn_s_setprio(0);

            if (q == 7) {
                // ---- epilogue: VALU-only reduce -> LDS key table ----
                const int g = nt * 4 + wn;
                #pragma unroll
                for (int mi = 0; mi < 4; ++mi) {
                    #pragma unroll
                    for (int r = 0; r < 4; ++r) {
                        float d = fmaf(-2.f, acc[mi][0][r], cq[0]);
                        #pragma unroll
                        for (int ni = 1; ni < 4; ++ni)
                            d = fminf(d, fmaf(-2.f, acc[mi][ni][r], cq[ni]));
                        d = dppmin16(d);
                        if (fr == 0)
                            tbl[wm * 64 + mi * 16 + kg * 4 + r][g] = fkey(d);
                    }
                }
                #pragma unroll
                for (int i = 0; i < 4; ++i)
                    #pragma unroll
                    for (int j = 0; j < 4; ++j)
                        acc[i][j] = (f32x4){0.f, 0.f, 0.f, 0.f};
            }
        }
    }

    // ---- flush key table: 8192 u32, 2-way LDS banks, coalesced global ----
    __syncthreads();
    #pragma unroll
    for (int i = 0; i < 8; ++i) {
        const int f2  = i * 512 + tid;             // uint2 index
        uint2 v = ((const uint2*)tbl)[f2];
        const int idx = f2 * 2;
        const int row = idx >> 6, col = idx & 63;
        *(uint2*)&blockmin[(size_t)(bm + row) * NG + nsplit * 64 + col] = v;
    }
}

// ---------------- rescore: one wave per row, barrier-free -------------------
__global__ __launch_bounds__(512, 2)
void rescore_wave_kernel(const float* __restrict__ X, const float* __restrict__ P,
                         const float* __restrict__ psq,
                         const unsigned* __restrict__ blockmin,
                         float* __restrict__ out) {
    __shared__ float Xs[8][256];
    __shared__ unsigned short wcand[8][512];
    __shared__ int wcnt[8];

    const int tid = threadIdx.x, lane = tid & 63, wv = tid >> 6;
    const int row = blockIdx.x * 8 + wv;

    ((f32x4*)Xs[wv])[lane] = ((const f32x4*)(X + (size_t)row * ND))[lane];
    if (lane == 0) wcnt[wv] = 0;

    const unsigned* bmr = blockmin + (size_t)row * NG;
    uint4 ka = ((const uint4*)bmr)[lane * 2];
    uint4 kb = ((const uint4*)bmr)[lane * 2 + 1];
    unsigned km = umin32(umin32(umin32(ka.x, ka.y), umin32(ka.z, ka.w)),
                         umin32(umin32(kb.x, kb.y), umin32(kb.z, kb.w)));
    #pragma unroll
    for (int m = 1; m < 64; m <<= 1) km = umin32(km, __shfl_xor(km, m));
    const unsigned thr = fkey(fkey_inv(km) + MARGIN);

    const unsigned k8[8] = {ka.x, ka.y, ka.z, ka.w, kb.x, kb.y, kb.z, kb.w};
    #pragma unroll
    for (int i = 0; i < 8; ++i)
        if (k8[i] <= thr)
            wcand[wv][atomicAdd(&wcnt[wv], 1)] = (unsigned short)(lane * 8 + i);
    LGKM(0);                             // same-wave DS ops complete, in order
    const int n = wcnt[wv];

    unsigned long long best = 0xFFFFFFFFFFFFFFFFull;
    const f32x4* x4 = (const f32x4*)Xs[wv];
    for (int c = 0; c < n; ++c) {
        const int col = (int)wcand[wv][c] * 64 + lane;
        const f32x4* p4 = (const f32x4*)(P + (size_t)col * ND);
        float s = 0.f;
        #pragma unroll 16
        for (int i = 0; i < 64; ++i) {
            f32x4 pv = p4[i], xv = x4[i];
            s = fmaf(xv.x, pv.x, s); s = fmaf(xv.y, pv.y, s);
            s = fmaf(xv.z, pv.z, s); s = fmaf(xv.w, pv.w, s);
        }
        float d = fmaf(-2.f, s, psq[col]);
        best = umin64(best, ((unsigned long long)fkey(d) << 32) |
                            (unsigned long long)(unsigned)col);
    }
    #pragma unroll
    for (int m = 1; m < 64; m <<= 1)
        best = umin64(best, __shfl_xor(best, m));
    const unsigned bc = (unsigned)(best & 0xFFFFFFFFull);
    ((f32x4*)(out + (size_t)row * ND))[lane] =
        ((const f32x4*)(P + (size_t)bc * ND))[lane];
}

// ======================= fallback: exact fp32 path (small ws) ===============
#define BM1 128
#define BN1 128
#define BK1 32
#define LDA1 132

__global__ void psq_init_kernel(const float* __restrict__ P, float* __restrict__ psq,
                                unsigned long long* __restrict__ minpack) {
    int row  = blockIdx.x * 4 + (threadIdx.x >> 6);
    int lane = threadIdx.x & 63;
    float4 p4 = ((const float4*)(P + (size_t)row * ND))[lane];
    float s = p4.x*p4.x + p4.y*p4.y + p4.z*p4.z + p4.w*p4.w;
    #pragma unroll
    for (int off = 32; off > 0; off >>= 1) s += __shfl_down(s, off);
    if (lane == 0) psq[row] = s;
    int gid = blockIdx.x * blockDim.x + threadIdx.x;
    if (gid < NB) minpack[gid] = 0xFFFFFFFFFFFFFFFFull;
}

__global__ __launch_bounds__(256, 2)
void nn_main_kernel(const float* __restrict__ X, const float* __restrict__ P,
                    const float* __restrict__ psq,
                    unsigned long long* __restrict__ minpack) {
    __shared__ __align__(16) char smem_raw[2 * BK1 * LDA1 * 4];
    float (*As)[LDA1] = (float (*)[LDA1])smem_raw;
    float (*Bs)[LDA1] = (float (*)[LDA1])(smem_raw + BK1 * LDA1 * 4);
    const int bm  = blockIdx.y * BM1;
    const int bn  = blockIdx.x * BN1;
    const int tid = threadIdx.x;
    const int tx  = tid & 15;
    const int ty  = tid >> 4;
    float acc[8][8];
    #pragma unroll
    for (int i = 0; i < 8; ++i)
        #pragma unroll
        for (int j = 0; j < 8; ++j) acc[i][j] = 0.f;
    const int lrow = tid >> 3;
    const int lk   = (tid & 7) * 4;
    for (int k0 = 0; k0 < ND; k0 += BK1) {
        #pragma unroll
        for (int p = 0; p < 4; ++p) {
            int r = p * 32 + lrow;
            float4 aa = *(const float4*)(X + (size_t)(bm + r) * ND + k0 + lk);
            As[lk+0][r] = aa.x; As[lk+1][r] = aa.y; As[lk+2][r] = aa.z; As[lk+3][r] = aa.w;
            float4 bb = *(const float4*)(P + (size_t)(bn + r) * ND + k0 + lk);
            Bs[lk+0][r] = bb.x; Bs[lk+1][r] = bb.y; Bs[lk+2][r] = bb.z; Bs[lk+3][r] = bb.w;
        }
        __syncthreads();
        #pragma unroll 4
        for (int k = 0; k < BK1; ++k) {
            float4 a0 = *(const float4*)&As[k][ty*8];
            float4 a1 = *(const float4*)&As[k][ty*8 + 4];
            float4 b0 = *(const float4*)&Bs[k][tx*4];
            float4 b1 = *(const float4*)&Bs[k][64 + tx*4];
            float av2[8] = {a0.x,a0.y,a0.z,a0.w,a1.x,a1.y,a1.z,a1.w};
            float bv2[8] = {b0.x,b0.y,b0.z,b0.w,b1.x,b1.y,b1.z,b1.w};
            #pragma unroll
            for (int i = 0; i < 8; ++i)
                #pragma unroll
                for (int j = 0; j < 8; ++j)
                    acc[i][j] = fmaf(av2[i], bv2[j], acc[i][j]);
        }
        __syncthreads();
    }
    unsigned long long (*red)[16] = (unsigned long long (*)[16])smem_raw;
    float cj[8];
    int   jglob[8];
    #pragma unroll
    for (int j = 0; j < 8; ++j) {
        int c = (j < 4) ? (tx*4 + j) : (64 + tx*4 + (j - 4));
        jglob[j] = bn + c;
        cj[j]    = psq[bn + c];
    }
    #pragma unroll
    for (int i = 0; i < 8; ++i) {
        float bestv = 0.f; unsigned bidx = 0u; bool first = true;
        #pragma unroll
        for (int j = 0; j < 8; ++j) {
            float s = fmaf(-2.f, acc[i][j], cj[j]);
            if (first || s < bestv) { bestv = s; bidx = (unsigned)jglob[j]; first = false; }
        }
        unsigned u = fkey(bestv);
        red[ty*8 + i][tx] = ((unsigned long long)u << 32) | (unsigned long long)bidx;
    }
    __syncthreads();
    if (tid < BM1) {
        unsigned long long m = red[tid][0];
        #pragma unroll
        for (int t = 1; t < 16; ++t) m = umin64(m, red[tid][t]);
        atomicMin(&minpack[bm + tid], m);
    }
}

__global__ void gather_kernel(const float* __restrict__ P,
                              const unsigned long long* __restrict__ minpack,
                              float* __restrict__ out) {
    int row = blockIdx.x;
    unsigned idx = (unsigned)(minpack[row] & 0xFFFFFFFFull);
    int lane = threadIdx.x;
    ((float4*)(out + (size_t)row * ND))[lane] =
        ((const float4*)(P + (size_t)idx * ND))[lane];
}

// ------------------------------------------------------------------- launch
extern "C" void kernel_launch(void* const* d_in, const int* in_sizes, int n_in,
                              void* d_out, int out_size, void* d_ws, size_t ws_size,
                              hipStream_t stream) {
    const float* X = (const float*)d_in[0];
    const float* P = (const float*)d_in[1];
    float* out = (float*)d_out;
    char* w = (char*)d_ws;

    if (ws_size >= WS_NEED) {
        float* psq = (float*)(w + OFF_PSQ);
        __bf16* Xb = (__bf16*)(w + OFF_XB);
        __bf16* Pb = (__bf16*)(w + OFF_PB);
        unsigned* blockmin = (unsigned*)(w + OFF_BM);

        prep_kernel<<<(NP + NB) / 4, 256, 0, stream>>>(X, P, psq, Xb, Pb);
        nn_dpp_kernel<<<(NB / 128) * NSPLIT, 512, 0, stream>>>(Xb, Pb, psq,
                                                               blockmin);
        rescore_wave_kernel<<<NB / 8, 512, 0, stream>>>(X, P, psq, blockmin, out);
    } else {
        float* psq = (float*)w;
        unsigned long long* minpack = (unsigned long long*)(w + (size_t)NP * 4);
        psq_init_kernel<<<NP / 4, 256, 0, stream>>>(P, psq, minpack);
        dim3 grid(NP / BN1, NB / BM1);
        nn_main_kernel<<<grid, dim3(256), 0, stream>>>(X, P, psq, minpack);
        gather_kernel<<<NB, 64, 0, stream>>>(P, minpack, out);
    }
}